// Round 1
// baseline (400.123 us; speedup 1.0000x reference)
//
#include <hip/hip_runtime.h>
#include <hip/hip_bf16.h>

#define D_ 128
#define NQ_ 256
#define NK_ 2048
#define P_TOT (NQ_ * NK_)   // 524288

typedef float f32x4 __attribute__((ext_vector_type(4)));
typedef short bf16x8 __attribute__((ext_vector_type(8)));

__device__ __forceinline__ unsigned short f2bf(float x) {
    union { float f; unsigned u; } v; v.f = x;
    unsigned r = v.u + 0x7FFFu + ((v.u >> 16) & 1u);   // RNE
    return (unsigned short)(r >> 16);
}

// ---------------- init: global-min cell ----------------
__global__ void k_init(unsigned* minw) { *minw = 0xFFFFFFFFu; }

// ---------------- qb[o][n] = b1[o] + sum_c wq[o][c] * x[c][n] ----------------
__global__ __launch_bounds__(256) void k_qb(const float* __restrict__ w1,
                                            const float* __restrict__ x,
                                            const float* __restrict__ b1,
                                            float* __restrict__ qb) {
    int idx = blockIdx.x * 256 + threadIdx.x;
    int o = idx >> 8, n = idx & 255;
    const float* wr = w1 + o * 384;
    float acc = b1[o];
#pragma unroll 4
    for (int c = 0; c < 128; ++c) acc = fmaf(wr[c], x[c * 256 + n], acc);
    qb[o * 256 + n] = acc;
}

// ---------------- kh[o][m] = sum_c wk[o][c] * source[c][m] ----------------
__global__ __launch_bounds__(256) void k_kh(const float* __restrict__ w1,
                                            const float* __restrict__ src,
                                            float* __restrict__ kh) {
    int idx = blockIdx.x * 256 + threadIdx.x;
    int o = idx >> 11, m = idx & 2047;
    const float* wr = w1 + o * 384 + 128;
    float acc = 0.f;
#pragma unroll 4
    for (int c = 0; c < 128; ++c) acc = fmaf(wr[c], src[c * 2048 + m], acc);
    kh[o * 2048 + m] = acc;
}

// ---------------- scores (raw) + global min ----------------
// dh = Wd @ dist via bf16 MFMA, fused epilogue: score = b2 + sum_o w2[o]*relu(dh+qb+kh)
__global__ __launch_bounds__(256, 2) void k_scores(
    const float* __restrict__ dist, const float* __restrict__ w1,
    const float* __restrict__ qb, const float* __restrict__ kh,
    const float* __restrict__ w2, const float* __restrict__ b2,
    float* __restrict__ scores, unsigned* __restrict__ minw) {
    __shared__ bf16x8 ldsA[8 * 4 * 64];   // 32 KB, [mt*4+kt][lane]
    int tid = threadIdx.x;

    // stage Wd (w1 cols 256..384) as bf16 A-fragments, fragment order
#pragma unroll
    for (int i = 0; i < 8; ++i) {
        int s = tid + i * 256;          // 0..2047 : o = s>>4, octet = s&15
        int o = s >> 4, oct = s & 15;
        const float* g = w1 + o * 384 + 256 + oct * 8;
        float4 f0 = *(const float4*)g;
        float4 f1 = *(const float4*)(g + 4);
        union { bf16x8 v; unsigned short u[8]; } pk;
        pk.u[0] = f2bf(f0.x); pk.u[1] = f2bf(f0.y); pk.u[2] = f2bf(f0.z); pk.u[3] = f2bf(f0.w);
        pk.u[4] = f2bf(f1.x); pk.u[5] = f2bf(f1.y); pk.u[6] = f2bf(f1.z); pk.u[7] = f2bf(f1.w);
        int mt = o >> 4, kt = oct >> 2;
        int lane = ((oct & 3) << 4) | (o & 15);
        ldsA[(mt * 4 + kt) * 64 + lane] = pk.v;
    }
    __syncthreads();

    int l = tid & 63, w = tid >> 6;
    int lg = l >> 4, c16 = l & 15;

    bf16x8 A[8][4];
#pragma unroll
    for (int mt = 0; mt < 8; ++mt)
#pragma unroll
        for (int kt = 0; kt < 4; ++kt)
            A[mt][kt] = ldsA[(mt * 4 + kt) * 64 + l];

    const float b2v = b2[0];
    float runmin = 1e30f;

    for (int cid = blockIdx.x; cid < P_TOT / 64; cid += gridDim.x) {
        int p0 = cid * 64 + w * 16;
        int n = p0 >> 11;
        int m = (p0 & 2047) | c16;
        f32x4 acc[8];
#pragma unroll
        for (int mt = 0; mt < 8; ++mt) acc[mt] = (f32x4){0.f, 0.f, 0.f, 0.f};

#pragma unroll
        for (int kt = 0; kt < 4; ++kt) {
            const float* bp = dist + (size_t)(kt * 32 + lg * 8) * (size_t)P_TOT
                                   + (size_t)(p0 + c16);
            float t[8];
#pragma unroll
            for (int b = 0; b < 8; ++b) t[b] = bp[(size_t)b * P_TOT];
            union { bf16x8 v; unsigned short u[8]; } bb;
#pragma unroll
            for (int b = 0; b < 8; ++b) bb.u[b] = f2bf(t[b]);
#pragma unroll
            for (int mt = 0; mt < 8; ++mt)
                acc[mt] = __builtin_amdgcn_mfma_f32_16x16x32_bf16(A[mt][kt], bb.v, acc[mt], 0, 0, 0);
        }

        float sp = 0.f;
#pragma unroll
        for (int mt = 0; mt < 8; ++mt) {
#pragma unroll
            for (int r = 0; r < 4; ++r) {
                int row = mt * 16 + lg * 4 + r;
                float t = acc[mt][r] + qb[row * 256 + n] + kh[row * 2048 + m];
                t = fmaxf(t, 0.f);
                sp = fmaf(w2[row], t, sp);
            }
        }
        sp += __shfl_xor(sp, 16);
        sp += __shfl_xor(sp, 32);
        float score = sp + b2v;
        if (l < 16) scores[(size_t)p0 + l] = score;

        float mn = score;
        mn = fminf(mn, __shfl_xor(mn, 1));
        mn = fminf(mn, __shfl_xor(mn, 2));
        mn = fminf(mn, __shfl_xor(mn, 4));
        mn = fminf(mn, __shfl_xor(mn, 8));
        runmin = fminf(runmin, mn);
    }

    union { float f; unsigned u; } e; e.f = runmin;
    unsigned key = (e.u & 0x80000000u) ? ~e.u : (e.u | 0x80000000u);
    if (l == 0) atomicMin(minw, key);
}

// ---------------- mask + softmax + message (fused) ----------------
__global__ __launch_bounds__(256) void k_softmax_msg(
    float* __restrict__ scores, const int* __restrict__ mask,
    const float* __restrict__ src, const unsigned* __restrict__ minw,
    float* __restrict__ msg) {
    int n = blockIdx.x, tid = threadIdx.x;
    __shared__ float sc[2048];
    __shared__ float red[8];

    unsigned key = *minw;
    union { float f; unsigned u; } d;
    d.u = (key & 0x80000000u) ? (key ^ 0x80000000u) : ~key;
    float neg = d.f - 20.f;

    float lmax = -1e30f;
#pragma unroll
    for (int i = 0; i < 8; ++i) {
        int m = tid + i * 256;
        float v = scores[n * 2048 + m];
        if (!mask[n * 2048 + m]) v += neg;
        scores[n * 2048 + m] = v;      // final (masked) scores out
        sc[m] = v;
        lmax = fmaxf(lmax, v);
    }
#pragma unroll
    for (int off = 1; off < 64; off <<= 1) lmax = fmaxf(lmax, __shfl_xor(lmax, off));
    int wv = tid >> 6;
    if ((tid & 63) == 0) red[wv] = lmax;
    __syncthreads();
    float smax = fmaxf(fmaxf(red[0], red[1]), fmaxf(red[2], red[3]));

    float lsum = 0.f;
#pragma unroll
    for (int i = 0; i < 8; ++i) {
        int m = tid + i * 256;
        float e = __expf(sc[m] - smax);
        sc[m] = e;
        lsum += e;
    }
#pragma unroll
    for (int off = 1; off < 64; off <<= 1) lsum += __shfl_xor(lsum, off);
    if ((tid & 63) == 0) red[4 + wv] = lsum;
    __syncthreads();
    float rinv = 1.f / (red[4] + red[5] + red[6] + red[7]);

    int l = tid & 63;
    for (int dd = 0; dd < 32; ++dd) {
        int dch = wv * 32 + dd;
        const float* sr = src + dch * 2048;
        float part = 0.f;
#pragma unroll
        for (int j = 0; j < 32; ++j) {
            int mm = l + j * 64;
            part = fmaf(sc[mm], sr[mm], part);
        }
#pragma unroll
        for (int off = 1; off < 64; off <<= 1) part += __shfl_xor(part, off);
        if (l == 0) msg[dch * 256 + n] = part * rinv;
    }
}

// ---------------- hid[o][n] = relu(b3[o] + sum_c w3[o][c]*cat[c][n]) ----------------
__global__ __launch_bounds__(256) void k_mlp1(const float* __restrict__ x,
                                              const float* __restrict__ msg,
                                              const float* __restrict__ w3,
                                              const float* __restrict__ b3,
                                              float* __restrict__ hid) {
    int o = blockIdx.x, n = threadIdx.x;
    const float* wr = w3 + o * 256;
    float acc = b3[o];
#pragma unroll 4
    for (int c = 0; c < 128; ++c) acc = fmaf(wr[c], x[c * 256 + n], acc);
#pragma unroll 4
    for (int c = 0; c < 128; ++c) acc = fmaf(wr[128 + c], msg[c * 256 + n], acc);
    hid[o * 256 + n] = fmaxf(acc, 0.f);
}

// ---------------- out[o][n] = b4[o] + sum_c w4[o][c]*hid[c][n] ----------------
__global__ __launch_bounds__(256) void k_mlp2(const float* __restrict__ hid,
                                              const float* __restrict__ w4,
                                              const float* __restrict__ b4,
                                              float* __restrict__ out) {
    int o = blockIdx.x, n = threadIdx.x;
    const float* wr = w4 + o * 256;
    float acc = b4[o];
#pragma unroll 4
    for (int c = 0; c < 256; ++c) acc = fmaf(wr[c], hid[c * 256 + n], acc);
    out[o * 256 + n] = acc;
}

extern "C" void kernel_launch(void* const* d_in, const int* in_sizes, int n_in,
                              void* d_out, int out_size, void* d_ws, size_t ws_size,
                              hipStream_t stream) {
    const float* x      = (const float*)d_in[0];
    const float* source = (const float*)d_in[1];
    const float* dist   = (const float*)d_in[2];
    const int*   mask   = (const int*)d_in[3];
    const float* w1     = (const float*)d_in[4];
    const float* b1     = (const float*)d_in[5];
    const float* w2     = (const float*)d_in[6];
    const float* b2     = (const float*)d_in[7];
    const float* w3     = (const float*)d_in[8];
    const float* b3     = (const float*)d_in[9];
    const float* w4     = (const float*)d_in[10];
    const float* b4     = (const float*)d_in[11];

    float* outp    = (float*)d_out;          // 128*256
    float* scoresp = outp + 32768;           // 256*2048 (raw, then masked in-place)

    float* ws   = (float*)d_ws;
    float* qb   = ws;                 // 32768
    float* kh   = ws + 32768;         // 262144
    float* msg  = ws + 294912;        // 32768
    float* hid  = ws + 327680;        // 65536
    unsigned* minw = (unsigned*)(ws + 393216);

    k_init<<<1, 1, 0, stream>>>(minw);
    k_qb<<<128, 256, 0, stream>>>(w1, x, b1, qb);
    k_kh<<<1024, 256, 0, stream>>>(w1, source, kh);
    k_scores<<<1024, 256, 0, stream>>>(dist, w1, qb, kh, w2, b2, scoresp, minw);
    k_softmax_msg<<<256, 256, 0, stream>>>(scoresp, mask, source, minw, msg);
    k_mlp1<<<256, 256, 0, stream>>>(x, msg, w3, b3, hid);
    k_mlp2<<<128, 256, 0, stream>>>(hid, w4, b4, outp);
}